// Round 12
// baseline (280.836 us; speedup 1.0000x reference)
//
#include <hip/hip_runtime.h>
#include <hip/hip_bf16.h>
#include <cstdint>

#define D_MODEL 4096
#define NFIB    64
#define NBATCH  4
#define LSEQ    4096
#define NTOK    (NBATCH * LSEQ)   // 16384
#define NSL     8                 // K slices in p1

typedef __attribute__((ext_vector_type(4))) float f32x4;
typedef __attribute__((ext_vector_type(8))) short bf16x8;

__device__ __forceinline__ unsigned short f2bf(float f) {
  unsigned int u = __builtin_bit_cast(unsigned int, f);
  u += 0x7FFFu + ((u >> 16) & 1u);
  return (unsigned short)(u >> 16);
}

__device__ __forceinline__ bf16x8 cvt8(f32x4 a, f32x4 b) {
  union { __hip_bfloat162 h2[4]; bf16x8 v; } u;
  u.h2[0] = __float22bfloat162_rn(make_float2(a[0], a[1]));
  u.h2[1] = __float22bfloat162_rn(make_float2(a[2], a[3]));
  u.h2[2] = __float22bfloat162_rn(make_float2(b[0], b[1]));
  u.h2[3] = __float22bfloat162_rn(make_float2(b[2], b[3]));
  return u.v;
}

__device__ __forceinline__ void addbf8(f32x4& x0, f32x4& x1, bf16x8 v) {
#pragma unroll
  for (int j = 0; j < 4; ++j)
    x0[j] += __builtin_bit_cast(float, (uint32_t)(unsigned short)v[j] << 16);
#pragma unroll
  for (int j = 0; j < 4; ++j)
    x1[j] += __builtin_bit_cast(float, (uint32_t)(unsigned short)v[j + 4] << 16);
}

// ---------------------------------------------------------------------------
// Blocks 0..3: S_b = Q_b - I = 2(I-A)^{-1}A (Gauss-Jordan, 2 barriers/pivot).
// Blocks 4..1027: W_down -> bf16 wave-swizzled Wd2.
// ---------------------------------------------------------------------------
__global__ __launch_bounds__(256) void prep1_kernel(const float* __restrict__ A,
                                                    const float* __restrict__ Wd,
                                                    float* __restrict__ S,
                                                    unsigned short* __restrict__ Wd2) {
  const int blk = blockIdx.x;
  if (blk >= NBATCH) {
    int idx = (blk - NBATCH) * 256 + threadIdx.x;
    int j    = idx & 7;
    int lane = (idx >> 3) & 63;
    int nf   = (idx >> 9) & 3;
    int ks   = idx >> 11;
    int row = nf * 16 + (lane & 15);
    int col = ks * 32 + (lane >> 4) * 8 + j;
    Wd2[idx] = f2bf(Wd[row * D_MODEL + col]);
    return;
  }
  __shared__ float M[64][66];
  __shared__ float R[64][66];
  const int b = blk;
  const int tid = threadIdx.x;
  const int k = tid & 63;
  const int g = tid >> 6;
  const float* Ab = A + b * 4096;
#pragma unroll
  for (int ii = 0; ii < 16; ++ii) {
    int i = g * 16 + ii;
    float a = Ab[i * 64 + k];
    M[i][k] = ((i == k) ? 1.0f : 0.0f) - a;
    R[i][k] = 2.0f * a;
  }
  for (int j = 0; j < 64; ++j) {
    __syncthreads();
    float pr  = 1.0f / M[j][j];
    float mjk = M[j][k], rjk = R[j][k];
    float f[16];
#pragma unroll
    for (int ii = 0; ii < 16; ++ii) f[ii] = M[g * 16 + ii][j] * pr;
    __syncthreads();
#pragma unroll
    for (int ii = 0; ii < 16; ++ii) {
      int i = g * 16 + ii;
      if (i != j) { M[i][k] -= f[ii] * mjk; R[i][k] -= f[ii] * rjk; }
    }
  }
  __syncthreads();
  float* Sb = S + b * 4096;
#pragma unroll
  for (int ii = 0; ii < 16; ++ii) {
    int i = g * 16 + ii;
    Sb[i * 64 + k] = R[i][k] / M[i][i];
  }
}

// ---------------------------------------------------------------------------
// U2[(((b*256+nt)*64+lane)*2+h)*8+j] = bf16(alpha*(Wup@S)[d][f]),
//   d = nt*16+(lane&15), f = h*32+(lane>>4)*8+j.
// ---------------------------------------------------------------------------
__global__ __launch_bounds__(256) void prep_u_kernel(const float* __restrict__ Wup,
                                                     const float* __restrict__ S,
                                                     const float* __restrict__ alpha_p,
                                                     unsigned short* __restrict__ U2) {
  __shared__ float Sl[4096];
  const int blk = blockIdx.x;          // 0..511
  const int b = blk >> 7;
  const int ntg = blk & 127;           // 2 nt per block
  const float* Sb = S + b * 4096;
  for (int i = threadIdx.x; i < 1024; i += 256)
    ((f32x4*)Sl)[i] = ((const f32x4*)Sb)[i];
  __syncthreads();

  const int t = threadIdx.x;
  const int nt   = ntg * 2 + (t >> 7);
  const int h    = (t >> 6) & 1;
  const int lane = t & 63;
  const int d = nt * 16 + (lane & 15);
  const int fbase = h * 32 + (lane >> 4) * 8;
  const float alpha = alpha_p[0];
  const f32x4* wr = (const f32x4*)(Wup + d * 64);

  float s[8];
#pragma unroll
  for (int j = 0; j < 8; ++j) s[j] = 0.f;
#pragma unroll
  for (int g4 = 0; g4 < 16; ++g4) {
    f32x4 wv = wr[g4];
#pragma unroll
    for (int gg = 0; gg < 4; ++gg) {
      const float* srow = &Sl[(g4 * 4 + gg) * 64 + fbase];
      float wvg = wv[gg];
#pragma unroll
      for (int j = 0; j < 8; ++j) s[j] += wvg * srow[j];
    }
  }
  bf16x8 v;
#pragma unroll
  for (int j = 0; j < 8; ++j) v[j] = (short)f2bf(alpha * s[j]);
  *(bf16x8*)(U2 + ((((size_t)b * 256 + nt) * 64 + lane) * 2 + h) * 8) = v;
}

// ---------------------------------------------------------------------------
// P1: partial F slices.  Grid 2048 = 256 token-groups(64) x 8 K-slices.
// Block 256 thr / 4 waves; wave = 16 tokens x 64 fibers x 512 K-cols.
// Per 64-col chunk: 4 CONTIGUOUS H loads (each 4 rows x 256B segments),
// stage to wave-private LDS [16][68] (no barriers), read A-frags from LDS,
// Wd2 B-frags from L2, 8 MFMA.  All HBM access is 256B-segment aligned.
// Partials -> Fpb[ks][token][fiber] bf16.
// ---------------------------------------------------------------------------
__global__ __launch_bounds__(256, 4) void p1_kernel(
    const float* __restrict__ H, const unsigned short* __restrict__ Wd2,
    unsigned short* __restrict__ Fpb) {
  const int blk = blockIdx.x;
  const int tg = blk >> 3;          // 0..255 : 64-token group
  const int ks = blk & 7;           // 0..7   : 512-col K slice
  const int tid = threadIdx.x;
  const int w = tid >> 6, l = tid & 63, lr = l & 15, lq = l >> 4;

  __shared__ float T[4][16][68];
  float (*Tw)[68] = T[w];

  const int rowW = tg * 64 + w * 16;            // wave's 16 tokens
  const int g16 = l >> 4;                        // row-in-group for staging
  const int c16 = (l & 15) * 4;                  // col (floats) for staging

  f32x4 acc[4];
#pragma unroll
  for (int nf = 0; nf < 4; ++nf) acc[nf] = (f32x4){0, 0, 0, 0};

  for (int ch = 0; ch < 8; ++ch) {
    const int colb = ks * 512 + ch * 64;
    // contiguous loads: 4 instrs x (4 rows x 256B)
    f32x4 hv[4];
#pragma unroll
    for (int i = 0; i < 4; ++i)
      hv[i] = *(const f32x4*)(H + (size_t)(rowW + 4 * i + g16) * D_MODEL + colb + c16);
#pragma unroll
    for (int i = 0; i < 4; ++i)
      *(f32x4*)&Tw[4 * i + g16][c16] = hv[i];

#pragma unroll
    for (int h = 0; h < 2; ++h) {
      f32x4 p0 = *(const f32x4*)&Tw[lr][h * 32 + lq * 8];
      f32x4 p1v = *(const f32x4*)&Tw[lr][h * 32 + lq * 8 + 4];
      bf16x8 afr = cvt8(p0, p1v);
      const int sg = ks * 16 + ch * 2 + h;
      const unsigned short* wp = Wd2 + (((size_t)sg * 4) * 64 + l) * 8;
#pragma unroll
      for (int nf = 0; nf < 4; ++nf) {
        bf16x8 bfr = *(const bf16x8*)(wp + (size_t)nf * 512);
        acc[nf] = __builtin_amdgcn_mfma_f32_16x16x32_bf16(afr, bfr, acc[nf], 0, 0, 0);
      }
    }
  }

  unsigned short* fp = Fpb + (size_t)ks * (NTOK * 64);
#pragma unroll
  for (int nf = 0; nf < 4; ++nf)
#pragma unroll
    for (int rr = 0; rr < 4; ++rr)
      fp[(size_t)(rowW + lq * 4 + rr) * 64 + nf * 16 + lr] = f2bf(acc[nf][rr]);
}

// ---------------------------------------------------------------------------
// PF: F2[t][f] = bf16( sum_ks Fpb[ks][t][f] ).  512 blocks, 8 bf16/thread.
// ---------------------------------------------------------------------------
__global__ __launch_bounds__(256, 8) void pf_kernel(
    const unsigned short* __restrict__ Fpb, unsigned short* __restrict__ F2) {
  const int idx = blockIdx.x * 256 + threadIdx.x;  // 0..131071, 8 elems each
  const size_t off = (size_t)idx * 8;
  f32x4 x0 = {0, 0, 0, 0}, x1 = {0, 0, 0, 0};
#pragma unroll
  for (int ks = 0; ks < NSL; ++ks)
    addbf8(x0, x1, *(const bf16x8*)(Fpb + (size_t)ks * (NTOK * 64) + off));
  *(bf16x8*)(F2 + off) = cvt8(x0, x1);
}

// ---------------------------------------------------------------------------
// P2: Out = H + F @ U^T.  Grid 4096 = 1024 token-tiles(16) x 4 col-chunks.
// Block 256 thr / 4 waves; wave = 16 tokens x 256 cols (4 sub-chunks of 64).
// Per sub-chunk: MFMA C from preloaded U (L2) + F (regs), C -> wave-private
// LDS [16][68], read back CONTIGUOUS, fuse with contiguous H load and
// contiguous Out store (4 instrs x 4 rows x 256B each). No barriers.
// ---------------------------------------------------------------------------
__global__ __launch_bounds__(256, 4) void p2_kernel(
    const float* __restrict__ H, const unsigned short* __restrict__ F2,
    const unsigned short* __restrict__ U2, float* __restrict__ Out) {
  const int blk = blockIdx.x;
  const int tile = blk >> 2;        // 0..1023 : 16-token tile
  const int cc4 = blk & 3;          // 0..3    : 1024-col chunk
  const int row0 = tile * 16;
  const int b = tile >> 8;
  const int tid = threadIdx.x;
  const int w = tid >> 6, l = tid & 63, lr = l & 15, lq = l >> 4;

  __shared__ float T[4][16][68];
  float (*Tw)[68] = T[w];

  const int g16 = l >> 4;
  const int c16 = (l & 15) * 4;

  // F fragments (token = lr, k = lq*8.. / 32+lq*8..)
  const unsigned short* fp = F2 + (size_t)(row0 + lr) * 64 + lq * 8;
  bf16x8 fb0 = *(const bf16x8*)fp;
  bf16x8 fb1 = *(const bf16x8*)(fp + 32);

  for (int sub = 0; sub < 4; ++sub) {
    const int colb = cc4 * 1024 + w * 256 + sub * 64;
    const int nt0 = colb >> 4;

    // contiguous H loads first (HBM stream)
    f32x4 hv[4];
#pragma unroll
    for (int i = 0; i < 4; ++i)
      hv[i] = *(const f32x4*)(H + (size_t)(row0 + 4 * i + g16) * D_MODEL + colb + c16);

    // U fragments (L2) + MFMA
    const unsigned short* ub = U2 + (((size_t)b * 256 + nt0) * 64 + l) * 16;
#pragma unroll
    for (int nt = 0; nt < 4; ++nt) {
      bf16x8 u0 = *(const bf16x8*)(ub + (size_t)nt * 1024);
      bf16x8 u1 = *(const bf16x8*)(ub + (size_t)nt * 1024 + 8);
      f32x4 c = {0, 0, 0, 0};
      c = __builtin_amdgcn_mfma_f32_16x16x32_bf16(u0, fb0, c, 0, 0, 0);
      c = __builtin_amdgcn_mfma_f32_16x16x32_bf16(u1, fb1, c, 0, 0, 0);
      // C fragment -> LDS (token lr, d = nt*16 + lq*4 + rr)
      *(f32x4*)&Tw[lr][nt * 16 + lq * 4] = c;
    }

    // contiguous read-back + residual + contiguous store
#pragma unroll
    for (int i = 0; i < 4; ++i) {
      f32x4 cv = *(const f32x4*)&Tw[4 * i + g16][c16];
      *(f32x4*)(Out + (size_t)(row0 + 4 * i + g16) * D_MODEL + colb + c16) = hv[i] + cv;
    }
  }
}

// ---------------------------------------------------------------------------
extern "C" void kernel_launch(void* const* d_in, const int* in_sizes, int n_in,
                              void* d_out, int out_size, void* d_ws, size_t ws_size,
                              hipStream_t stream) {
  const float* h_t    = (const float*)d_in[0];
  // d_in[1] = z0 (unused by the reference)
  const float* A_u    = (const float*)d_in[2];
  const float* alpha  = (const float*)d_in[3];
  const float* W_down = (const float*)d_in[4];
  const float* W_up   = (const float*)d_in[5];
  float* out = (float*)d_out;

  char* ws = (char*)d_ws;
  float*          S   = (float*)ws;                               // 64 KiB
  unsigned short* Wd2 = (unsigned short*)(ws + (64 << 10));       // 512 KiB
  unsigned short* U2  = (unsigned short*)(ws + (576 << 10));      // 2 MiB
  unsigned short* Fpb = (unsigned short*)(ws + (2624 << 10));     // 16 MiB (8 slices)
  unsigned short* F2  = (unsigned short*)(ws + (19008 << 10));    // 2 MiB

  prep1_kernel<<<NBATCH + 1024, 256, 0, stream>>>(A_u, W_down, S, Wd2);
  prep_u_kernel<<<512, 256, 0, stream>>>(W_up, S, alpha, U2);
  p1_kernel<<<2048, 256, 0, stream>>>(h_t, Wd2, Fpb);
  pf_kernel<<<512, 256, 0, stream>>>(Fpb, F2);
  p2_kernel<<<4096, 256, 0, stream>>>(h_t, F2, U2, out);
}